// Round 3
// baseline (761.601 us; speedup 1.0000x reference)
//
#include <hip/hip_runtime.h>

#define NN 100000
#define BQ 1024
#define EE 262144
#define KTOP 20

typedef unsigned long long ull;
typedef __attribute__((ext_vector_type(8))) short bf16x8;
typedef __attribute__((ext_vector_type(4))) float f32x4;

__device__ __forceinline__ ull enc64(double d) {
  ull u = (ull)__double_as_longlong(d);
  return (u >> 63) ? ~u : (u | 0x8000000000000000ull);
}
__device__ __forceinline__ double dec64(ull u) {
  ull b = (u >> 63) ? (u & 0x7FFFFFFFFFFFFFFFull) : ~u;
  return __longlong_as_double((long long)b);
}

__device__ __forceinline__ unsigned short f2bf(float f) {
  unsigned u = __float_as_uint(f);
  u += 0x7fff + ((u >> 16) & 1);
  return (unsigned short)(u >> 16);
}
__device__ __forceinline__ float bf2f(unsigned short h) {
  return __uint_as_float(((unsigned)h) << 16);
}
// 8 f32 -> hi/lo bf16 fragments
__device__ __forceinline__ void cvt8(float4 x, float4 y, bf16x8& hi, bf16x8& lo) {
  float a[8] = {x.x, x.y, x.z, x.w, y.x, y.y, y.z, y.w};
#pragma unroll
  for (int j = 0; j < 8; j++) {
    unsigned short h = f2bf(a[j]);
    float r = a[j] - bf2f(h);
    hi[j] = (short)h;
    lo[j] = (short)f2bf(r);
  }
}

// ---------------- init ----------------
__global__ void k_init(ull* __restrict__ menc, double* __restrict__ s,
                       float* __restrict__ appears, float* __restrict__ out_score) {
  int i = blockIdx.x * 256 + threadIdx.x;
  int st = gridDim.x * 256;
  for (int n = i; n < NN; n += st) {
    menc[n] = 0ull;
    s[n] = 0.0;
    appears[n] = 0.f;
    out_score[n] = 0.f;
  }
}

// ---------------- M = Wq^T Wk (f64 acc, f32 store) ----------------
__global__ void k_matM(const float* __restrict__ Wq, const float* __restrict__ Wk,
                       float* __restrict__ M) {
  int x = blockIdx.x;
  int y = blockIdx.y * 256 + threadIdx.x;
  double acc = 0.0;
  for (int a = 0; a < 512; a++)
    acc += (double)Wq[a * 512 + x] * (double)Wk[a * 512 + y];
  M[x * 512 + y] = (float)acc;
}

__global__ void k_transpose(const float* __restrict__ M, float* __restrict__ MT) {
  int x = blockIdx.x;
  int y = blockIdx.y * 256 + threadIdx.x;
  MT[y * 512 + x] = M[x * 512 + y];
}

// ---------------- pack B operands as transposed bf16 hi/lo ----------------
// wn (3 panels of [c][k]): panel0 BT=MT[c][k]; panel1 BT=MT[128+c][k]; panel2 BT=M[128+c][k]
// m11 BT[c][k] = MT[128+c][128+k] ; wl BT[j][k] = Wl[j*128+k]
__global__ void k_pack(const float* __restrict__ M, const float* __restrict__ MT,
                       const float* __restrict__ Wl,
                       short* __restrict__ wn_hi, short* __restrict__ wn_lo,
                       short* __restrict__ m11_hi, short* __restrict__ m11_lo,
                       short* __restrict__ wl_hi, short* __restrict__ wl_lo) {
  int idx = blockIdx.x * 256 + threadIdx.x;
  if (idx >= 5 * 16384) return;
  int arr = idx >> 14;
  int j = idx & 16383;
  int c = j >> 7, k = j & 127;
  float v;
  short *dh, *dl;
  if (arr == 0)      { v = MT[(size_t)c * 512 + k];               dh = wn_hi;          dl = wn_lo; }
  else if (arr == 1) { v = MT[(size_t)(128 + c) * 512 + k];       dh = wn_hi + 16384;  dl = wn_lo + 16384; }
  else if (arr == 2) { v = M[(size_t)(128 + c) * 512 + k];        dh = wn_hi + 32768;  dl = wn_lo + 32768; }
  else if (arr == 3) { v = MT[(size_t)(128 + c) * 512 + 128 + k]; dh = m11_hi;         dl = m11_lo; }
  else               { v = Wl[(size_t)c * 128 + k];               dh = wl_hi;          dl = wl_lo; }
  unsigned short h = f2bf(v);
  float r = v - bf2f(h);
  dh[j] = (short)h;
  dl[j] = (short)f2bf(r);
}

// ---------------- per-query vectors (f64 acc) ----------------
__global__ void k_pq(const float* __restrict__ M, const float* __restrict__ MT,
                     const float* __restrict__ qsA, const float* __restrict__ qrA,
                     float* __restrict__ Qv, double* __restrict__ cq) {
  int b = blockIdx.x, d = threadIdx.x;  // 128 threads
  __shared__ float qs[128], qr[128];
  qs[d] = qsA[b * 128 + d];
  qr[d] = qrA[b * 128 + d];
  __syncthreads();
  double uh = 0, ui = 0, ur = 0;
  for (int x = 0; x < 128; x++) {
    double qsx = qs[x], qrx = qr[x];
    uh += qsx * (double)M[(256 + x) * 512 + d]        + qrx * (double)M[(384 + x) * 512 + d];
    ur += qsx * (double)M[(256 + x) * 512 + 128 + d]  + qrx * (double)M[(384 + x) * 512 + 128 + d];
    ui += qsx * (double)MT[(256 + x) * 512 + d]       + qrx * (double)MT[(384 + x) * 512 + d];
    ur += qsx * (double)MT[(256 + x) * 512 + 128 + d] + qrx * (double)MT[(384 + x) * 512 + 128 + d];
  }
  Qv[b * 384 + d]       = (float)uh;
  Qv[b * 384 + 128 + d] = (float)ui;
  Qv[b * 384 + 256 + d] = (float)ur;
  double t1 = 0, t2 = 0;
  for (int y = 0; y < 128; y++) {
    double qsy = qs[y], qry = qr[y];
    t1 += qsy * (double)MT[(256 + y) * 512 + 256 + d] + qry * (double)MT[(384 + y) * 512 + 256 + d];
    t2 += qsy * (double)MT[(256 + y) * 512 + 384 + d] + qry * (double)MT[(384 + y) * 512 + 384 + d];
  }
  double cp = (double)qs[d] * t1 + (double)qr[d] * t2;
  for (int off = 32; off; off >>= 1) cp += __shfl_down(cp, off, 64);
  __shared__ double red[2];
  if ((d & 63) == 0) red[d >> 6] = cp;
  __syncthreads();
  if (d == 0) cq[b] = red[0] + red[1];
}

// ---------------- T = node_repr @ Wnode via MFMA bf16-split ----------------
__global__ __launch_bounds__(256) void k_gemm_node(const float* __restrict__ A,
                                                   const short* __restrict__ WT_hi,
                                                   const short* __restrict__ WT_lo,
                                                   float* __restrict__ T) {
  __shared__ __align__(16) float As[64][132];
  int t = threadIdx.x;
  int row0 = blockIdx.x * 64;
  int panel = blockIdx.y;
#pragma unroll
  for (int i = 0; i < 8; i++) {
    int fi = t + i * 256;
    int r = fi >> 5, c4 = (fi & 31) * 4;
    float4 v = make_float4(0.f, 0.f, 0.f, 0.f);
    if (row0 + r < NN) v = *(const float4*)(A + (size_t)(row0 + r) * 128 + c4);
    *(float4*)&As[r][c4] = v;
  }
  __syncthreads();
  int w = t >> 6, l = t & 63;
  int rloc = w * 16 + (l & 15);
  int kq = (l >> 4) * 8;
  const short* bh = WT_hi + panel * 16384 + (l & 15) * 128;
  const short* blo = WT_lo + panel * 16384 + (l & 15) * 128;
  f32x4 acc[8];
#pragma unroll
  for (int ct = 0; ct < 8; ct++)
#pragma unroll
    for (int j = 0; j < 4; j++) acc[ct][j] = 0.f;
#pragma unroll
  for (int kt = 0; kt < 4; kt++) {
    int kb = kt * 32 + kq;
    float4 x = *(const float4*)&As[rloc][kb];
    float4 y = *(const float4*)&As[rloc][kb + 4];
    bf16x8 ah, al;
    cvt8(x, y, ah, al);
#pragma unroll
    for (int ct = 0; ct < 8; ct++) {
      bf16x8 bhv = *(const bf16x8*)(bh + ct * 2048 + kb);
      bf16x8 blv = *(const bf16x8*)(blo + ct * 2048 + kb);
      acc[ct] = __builtin_amdgcn_mfma_f32_16x16x32_bf16(ah, bhv, acc[ct], 0, 0, 0);
      acc[ct] = __builtin_amdgcn_mfma_f32_16x16x32_bf16(al, bhv, acc[ct], 0, 0, 0);
      acc[ct] = __builtin_amdgcn_mfma_f32_16x16x32_bf16(ah, blv, acc[ct], 0, 0, 0);
    }
  }
  int rbase = row0 + w * 16 + (l >> 4) * 4;
  int cbase = panel * 128 + (l & 15);
#pragma unroll
  for (int ct = 0; ct < 8; ct++) {
#pragma unroll
    for (int reg = 0; reg < 4; reg++) {
      int r = rbase + reg;
      if (r < NN) T[(size_t)r * 384 + cbase + ct * 16] = acc[ct][reg];
    }
  }
}

// ---------------- q11[e] = r^T M11 r via MFMA (P = R@M11, then dot R) ----------------
__global__ __launch_bounds__(256) void k_q11(const float* __restrict__ rel,
                                             const short* __restrict__ M11T_hi,
                                             const short* __restrict__ M11T_lo,
                                             float* __restrict__ q11) {
  __shared__ __align__(16) float Rs[64][132];
  int t = threadIdx.x;
  int e0 = blockIdx.x * 64;
#pragma unroll
  for (int i = 0; i < 8; i++) {
    int fi = t + i * 256;
    int r = fi >> 5, c4 = (fi & 31) * 4;
    *(float4*)&Rs[r][c4] = *(const float4*)(rel + (size_t)(e0 + r) * 128 + c4);
  }
  __syncthreads();
  int w = t >> 6, l = t & 63;
  int rloc = w * 16 + (l & 15);
  int kq = (l >> 4) * 8;
  const short* bh = M11T_hi + (l & 15) * 128;
  const short* blo = M11T_lo + (l & 15) * 128;
  f32x4 acc[8];
#pragma unroll
  for (int ct = 0; ct < 8; ct++)
#pragma unroll
    for (int j = 0; j < 4; j++) acc[ct][j] = 0.f;
#pragma unroll
  for (int kt = 0; kt < 4; kt++) {
    int kb = kt * 32 + kq;
    float4 x = *(const float4*)&Rs[rloc][kb];
    float4 y = *(const float4*)&Rs[rloc][kb + 4];
    bf16x8 ah, al;
    cvt8(x, y, ah, al);
#pragma unroll
    for (int ct = 0; ct < 8; ct++) {
      bf16x8 bhv = *(const bf16x8*)(bh + ct * 2048 + kb);
      bf16x8 blv = *(const bf16x8*)(blo + ct * 2048 + kb);
      acc[ct] = __builtin_amdgcn_mfma_f32_16x16x32_bf16(ah, bhv, acc[ct], 0, 0, 0);
      acc[ct] = __builtin_amdgcn_mfma_f32_16x16x32_bf16(al, bhv, acc[ct], 0, 0, 0);
      acc[ct] = __builtin_amdgcn_mfma_f32_16x16x32_bf16(ah, blv, acc[ct], 0, 0, 0);
    }
  }
  // dot P row with R row, reduce across the 16-lane col groups
  int rq = (l >> 4) * 4;
  float p[4] = {0.f, 0.f, 0.f, 0.f};
#pragma unroll
  for (int ct = 0; ct < 8; ct++) {
    int c = ct * 16 + (l & 15);
#pragma unroll
    for (int reg = 0; reg < 4; reg++)
      p[reg] += acc[ct][reg] * Rs[w * 16 + rq + reg][c];
  }
#pragma unroll
  for (int reg = 0; reg < 4; reg++) {
    p[reg] += __shfl_xor(p[reg], 1, 64);
    p[reg] += __shfl_xor(p[reg], 2, 64);
    p[reg] += __shfl_xor(p[reg], 4, 64);
    p[reg] += __shfl_xor(p[reg], 8, 64);
  }
  if ((l & 15) == 0) {
#pragma unroll
    for (int reg = 0; reg < 4; reg++) q11[e0 + w * 16 + rq + reg] = p[reg];
  }
}

// ---------------- per-edge logits (wave per edge) + segment max ----------------
__global__ void k_logits(const int* __restrict__ edges, const float* __restrict__ nrep,
                         const float* __restrict__ rel, const float* __restrict__ T,
                         const float* __restrict__ Qv, const double* __restrict__ cq,
                         const float* __restrict__ q11, double* __restrict__ logits,
                         ull* __restrict__ menc) {
  int lane = threadIdx.x & 63;
  int wid = blockIdx.x * (blockDim.x >> 6) + (threadIdx.x >> 6);
  int nw = gridDim.x * (blockDim.x >> 6);
  for (int e = wid; e < EE; e += nw) {
    int eg = edges[(size_t)e * 8 + 0];
    int vi = edges[(size_t)e * 8 + 6];
    int vj = edges[(size_t)e * 8 + 7];
    const float* Tvi = T + (size_t)vi * 384;
    const float* Tvj = T + (size_t)vj * 384;
    const float* q = Qv + (size_t)eg * 384;
    const float* hi = nrep + (size_t)vi * 128;
    const float* hj = nrep + (size_t)vj * 128;
    const float* re = rel + (size_t)e * 128;
    int d0 = lane * 2;
    float2 g   = *(const float2*)&Tvi[d0];
    float2 h1  = *(const float2*)&Tvi[128 + d0];
    float2 jj  = *(const float2*)&Tvj[256 + d0];
    float2 uh  = *(const float2*)&q[d0];
    float2 uiq = *(const float2*)&q[128 + d0];
    float2 urq = *(const float2*)&q[256 + d0];
    float2 hvi = *(const float2*)&hi[d0];
    float2 hvj = *(const float2*)&hj[d0];
    float2 rr  = *(const float2*)&re[d0];
    float v = (g.x + uh.x) * hvj.x + (g.y + uh.y) * hvj.y
            + uiq.x * hvi.x + uiq.y * hvi.y
            + (h1.x + jj.x + urq.x) * rr.x
            + (h1.y + jj.y + urq.y) * rr.y;
    for (int off = 32; off; off >>= 1) v += __shfl_down(v, off, 64);
    if (lane == 0) {
      double l2 = (double)v + cq[eg] + (double)q11[e];
      logits[e] = l2;
      atomicMax(&menc[vi], enc64(l2));
    }
  }
}

// ---------------- exp + segment sum (f64) ----------------
__global__ void k_exp(const int* __restrict__ edges, const ull* __restrict__ menc,
                      const double* __restrict__ logits, double* __restrict__ ex,
                      double* __restrict__ s) {
  int i = blockIdx.x * 256 + threadIdx.x;
  int st = gridDim.x * 256;
  for (int e = i; e < EE; e += st) {
    int vi = edges[(size_t)e * 8 + 6];
    double m = dec64(menc[vi]);
    double v = exp(logits[e] - m);
    ex[e] = v;
    atomicAdd(&s[vi], v);
  }
}

__global__ void k_zero_agg(float4* __restrict__ agg) {
  int i = blockIdx.x * 256 + threadIdx.x;
  int st = gridDim.x * 256;
  const int n4 = NN * 32;
  for (int n = i; n < n4; n += st) agg[n] = make_float4(0.f, 0.f, 0.f, 0.f);
}

// ---------------- top-20 per query (lower-index tie-break) + scatter ----------------
__global__ void k_topk(const double* __restrict__ ex, const double* __restrict__ s,
                       const float* __restrict__ nscore, const int* __restrict__ edges,
                       const float* __restrict__ nrep, float* __restrict__ out_score,
                       float* __restrict__ agg, float* __restrict__ appears) {
  int b = blockIdx.x, t = threadIdx.x;  // 256 threads
  int e = b * 256 + t;
  int vi_t = edges[(size_t)e * 8 + 6];
  double v = ex[e] / s[vi_t] * (double)nscore[vi_t];
  __shared__ double wv[4];
  __shared__ int wi[4];
  __shared__ int winners[KTOP];
  for (int k = 0; k < KTOP; k++) {
    double bv = v;
    int bi = t;
    for (int off = 32; off; off >>= 1) {
      double ov = __shfl_down(bv, off, 64);
      int oi = __shfl_down(bi, off, 64);
      if (ov > bv || (ov == bv && oi < bi)) { bv = ov; bi = oi; }
    }
    if ((t & 63) == 0) { wv[t >> 6] = bv; wi[t >> 6] = bi; }
    __syncthreads();
    if (t == 0) {
      double best = wv[0];
      int besti = wi[0];
      for (int w = 1; w < 4; w++)
        if (wv[w] > best || (wv[w] == best && wi[w] < besti)) { best = wv[w]; besti = wi[w]; }
      winners[k] = besti;
    }
    __syncthreads();
    if (t == winners[k]) v = -1.0;
  }
  for (int k = 0; k < KTOP; k++) {
    int we = b * 256 + winners[k];
    int vi = edges[(size_t)we * 8 + 6];
    int vj = edges[(size_t)we * 8 + 7];
    double sm = ex[we] / s[vi];
    if (t < 128) {
      atomicAdd(&agg[(size_t)vi * 128 + t], (float)sm * nrep[(size_t)vj * 128 + t]);
    } else if (t == 128) {
      atomicAdd(&out_score[vj], (float)(sm * (double)nscore[vi]));
    } else if (t == 129) {
      appears[vi] = 1.f;
    }
  }
}

// ---------------- final: leaky_relu((agg + coef*h) @ W_lin^T + b) via MFMA ----------------
__global__ __launch_bounds__(256) void k_final(const float* __restrict__ agg,
                                               const float* __restrict__ appears,
                                               const float* __restrict__ nrep,
                                               const short* __restrict__ Wl_hi,
                                               const short* __restrict__ Wl_lo,
                                               const float* __restrict__ bl,
                                               float* __restrict__ outr) {
  __shared__ __align__(16) float Xs[64][132];
  int t = threadIdx.x;
  int row0 = blockIdx.x * 64;
#pragma unroll
  for (int i = 0; i < 8; i++) {
    int fi = t + i * 256;
    int r = fi >> 5, c4 = (fi & 31) * 4;
    int rr = row0 + r;
    float4 v = make_float4(0.f, 0.f, 0.f, 0.f);
    if (rr < NN) {
      float4 ag = *(const float4*)(agg + (size_t)rr * 128 + c4);
      float4 h = *(const float4*)(nrep + (size_t)rr * 128 + c4);
      float coef = (appears[rr] > 0.f) ? 0.f : 1.f;
      v.x = ag.x + coef * h.x;
      v.y = ag.y + coef * h.y;
      v.z = ag.z + coef * h.z;
      v.w = ag.w + coef * h.w;
    }
    *(float4*)&Xs[r][c4] = v;
  }
  __syncthreads();
  int w = t >> 6, l = t & 63;
  int rloc = w * 16 + (l & 15);
  int kq = (l >> 4) * 8;
  const short* bh = Wl_hi + (l & 15) * 128;
  const short* blo = Wl_lo + (l & 15) * 128;
  f32x4 acc[8];
#pragma unroll
  for (int ct = 0; ct < 8; ct++)
#pragma unroll
    for (int j = 0; j < 4; j++) acc[ct][j] = 0.f;
#pragma unroll
  for (int kt = 0; kt < 4; kt++) {
    int kb = kt * 32 + kq;
    float4 x = *(const float4*)&Xs[rloc][kb];
    float4 y = *(const float4*)&Xs[rloc][kb + 4];
    bf16x8 ah, al;
    cvt8(x, y, ah, al);
#pragma unroll
    for (int ct = 0; ct < 8; ct++) {
      bf16x8 bhv = *(const bf16x8*)(bh + ct * 2048 + kb);
      bf16x8 blv = *(const bf16x8*)(blo + ct * 2048 + kb);
      acc[ct] = __builtin_amdgcn_mfma_f32_16x16x32_bf16(ah, bhv, acc[ct], 0, 0, 0);
      acc[ct] = __builtin_amdgcn_mfma_f32_16x16x32_bf16(al, bhv, acc[ct], 0, 0, 0);
      acc[ct] = __builtin_amdgcn_mfma_f32_16x16x32_bf16(ah, blv, acc[ct], 0, 0, 0);
    }
  }
  int rbase = row0 + w * 16 + (l >> 4) * 4;
#pragma unroll
  for (int ct = 0; ct < 8; ct++) {
    int c = ct * 16 + (l & 15);
#pragma unroll
    for (int reg = 0; reg < 4; reg++) {
      int r = rbase + reg;
      if (r < NN) {
        float y = acc[ct][reg] + bl[c];
        outr[(size_t)r * 128 + c] = (y > 0.f) ? y : 0.01f * y;
      }
    }
  }
}

extern "C" void kernel_launch(void* const* d_in, const int* in_sizes, int n_in,
                              void* d_out, int out_size, void* d_ws, size_t ws_size,
                              hipStream_t stream) {
  const float* node_score = (const float*)d_in[0];
  const float* node_repr  = (const float*)d_in[1];
  const float* rel_emb    = (const float*)d_in[2];
  const float* q_src      = (const float*)d_in[3];
  const float* q_rel      = (const float*)d_in[4];
  const float* Wq         = (const float*)d_in[5];
  const float* Wk         = (const float*)d_in[6];
  const float* W_lin      = (const float*)d_in[7];
  const float* b_lin      = (const float*)d_in[8];
  const int*   edges      = (const int*)d_in[9];

  char* ws = (char*)d_ws;
  size_t off = 0;
  auto carve = [&](size_t bytes) -> void* {
    void* p = ws + off;
    off += (bytes + 255) & ~(size_t)255;
    return p;
  };
  float*  M      = (float*)carve(512 * 512 * 4);
  float*  MT     = (float*)carve(512 * 512 * 4);
  short*  wn_hi  = (short*)carve(3 * 16384 * 2);
  short*  wn_lo  = (short*)carve(3 * 16384 * 2);
  short*  m11_hi = (short*)carve(16384 * 2);
  short*  m11_lo = (short*)carve(16384 * 2);
  short*  wl_hi  = (short*)carve(16384 * 2);
  short*  wl_lo  = (short*)carve(16384 * 2);
  float*  Qv     = (float*)carve((size_t)BQ * 384 * 4);
  double* cq     = (double*)carve((size_t)BQ * 8);
  double* logits = (double*)carve((size_t)EE * 8);
  float*  q11    = (float*)carve((size_t)EE * 4);
  ull*    menc   = (ull*)carve((size_t)NN * 8);
  double* s      = (double*)carve((size_t)NN * 8);
  double* ex     = (double*)carve((size_t)EE * 8);
  float*  appears= (float*)carve((size_t)NN * 4);
  float*  T      = (float*)carve((size_t)NN * 384 * 4);
  float*  agg    = T;  // alias: T dead after k_logits; zeroed before reuse

  float* out_score = (float*)d_out;
  float* out_repr  = (float*)d_out + NN;

  k_init<<<512, 256, 0, stream>>>(menc, s, appears, out_score);
  k_matM<<<dim3(512, 2), 256, 0, stream>>>(Wq, Wk, M);
  k_transpose<<<dim3(512, 2), 256, 0, stream>>>(M, MT);
  k_pack<<<320, 256, 0, stream>>>(M, MT, W_lin, wn_hi, wn_lo, m11_hi, m11_lo, wl_hi, wl_lo);
  k_pq<<<BQ, 128, 0, stream>>>(M, MT, q_src, q_rel, Qv, cq);
  k_gemm_node<<<dim3(1563, 3), 256, 0, stream>>>(node_repr, wn_hi, wn_lo, T);
  k_q11<<<4096, 256, 0, stream>>>(rel_emb, m11_hi, m11_lo, q11);
  k_logits<<<2048, 256, 0, stream>>>(edges, node_repr, rel_emb, T, Qv, cq, q11, logits, menc);
  k_zero_agg<<<2048, 256, 0, stream>>>((float4*)agg);
  k_exp<<<1024, 256, 0, stream>>>(edges, menc, logits, ex, s);
  k_topk<<<BQ, 256, 0, stream>>>(ex, s, node_score, edges, node_repr, out_score, agg, appears);
  k_final<<<1563, 256, 0, stream>>>(agg, appears, node_repr, wl_hi, wl_lo, b_lin, out_repr);
}

// Round 4
// 536.203 us; speedup vs baseline: 1.4204x; 1.4204x over previous
//
#include <hip/hip_runtime.h>

#define NN 100000
#define BQ 1024
#define EE 262144
#define KTOP 20

typedef unsigned long long ull;
typedef __attribute__((ext_vector_type(8))) short bf16x8;
typedef __attribute__((ext_vector_type(4))) float f32x4;

__device__ __forceinline__ ull enc64(double d) {
  ull u = (ull)__double_as_longlong(d);
  return (u >> 63) ? ~u : (u | 0x8000000000000000ull);
}
__device__ __forceinline__ double dec64(ull u) {
  ull b = (u >> 63) ? (u & 0x7FFFFFFFFFFFFFFFull) : ~u;
  return __longlong_as_double((long long)b);
}

__device__ __forceinline__ unsigned short f2bf(float f) {
  unsigned u = __float_as_uint(f);
  u += 0x7fff + ((u >> 16) & 1);
  return (unsigned short)(u >> 16);
}
__device__ __forceinline__ float bf2f(unsigned short h) {
  return __uint_as_float(((unsigned)h) << 16);
}
// 8 f32 -> hi/lo bf16 fragments
__device__ __forceinline__ void cvt8(float4 x, float4 y, bf16x8& hi, bf16x8& lo) {
  float a[8] = {x.x, x.y, x.z, x.w, y.x, y.y, y.z, y.w};
#pragma unroll
  for (int j = 0; j < 8; j++) {
    unsigned short h = f2bf(a[j]);
    float r = a[j] - bf2f(h);
    hi[j] = (short)h;
    lo[j] = (short)f2bf(r);
  }
}

// ---------------- init ----------------
__global__ void k_init(ull* __restrict__ menc, double* __restrict__ s,
                       float* __restrict__ appears, float* __restrict__ out_score) {
  int i = blockIdx.x * 256 + threadIdx.x;
  int st = gridDim.x * 256;
  for (int n = i; n < NN; n += st) {
    menc[n] = 0ull;
    s[n] = 0.0;
    appears[n] = 0.f;
    out_score[n] = 0.f;
  }
}

// ---------------- M = Wq^T Wk (f64 acc, f32 store) ----------------
__global__ void k_matM(const float* __restrict__ Wq, const float* __restrict__ Wk,
                       float* __restrict__ M) {
  int x = blockIdx.x;
  int y = blockIdx.y * 256 + threadIdx.x;
  double acc = 0.0;
  for (int a = 0; a < 512; a++)
    acc += (double)Wq[a * 512 + x] * (double)Wk[a * 512 + y];
  M[x * 512 + y] = (float)acc;
}

__global__ void k_transpose(const float* __restrict__ M, float* __restrict__ MT) {
  int x = blockIdx.x;
  int y = blockIdx.y * 256 + threadIdx.x;
  MT[y * 512 + x] = M[x * 512 + y];
}

// ---------------- pack B operands as bf16 hi/lo in FRAGMENT ORDER ----------------
// Fragment order: chunk g = ct*4+kt (ct: 16-col tile, kt: 32-k step), lane l, elem j
//   dest[(g*64 + l)*8 + j] = BT[c][k], c = ct*16 + (l&15), k = kt*32 + (l>>4)*8 + j
// BT sources: wn panel0 = MT[c][k]; panel1 = MT[128+c][k]; panel2 = M[128+c][k]
//             m11 = MT[128+c][128+k] ; wl = Wl[c*128+k]
__global__ void k_pack(const float* __restrict__ M, const float* __restrict__ MT,
                       const float* __restrict__ Wl,
                       short* __restrict__ wn_hi, short* __restrict__ wn_lo,
                       short* __restrict__ m11_hi, short* __restrict__ m11_lo,
                       short* __restrict__ wl_hi, short* __restrict__ wl_lo) {
  int idx = blockIdx.x * 256 + threadIdx.x;
  if (idx >= 5 * 16384) return;
  int arr = idx >> 14;
  int j16 = idx & 16383;
  int g = j16 >> 9;          // 0..31
  int l = (j16 >> 3) & 63;   // lane
  int jj = j16 & 7;
  int c = (g >> 2) * 16 + (l & 15);
  int k = (g & 3) * 32 + ((l >> 4) << 3) + jj;
  float v;
  short *dh, *dl;
  if (arr == 0)      { v = MT[(size_t)c * 512 + k];               dh = wn_hi;          dl = wn_lo; }
  else if (arr == 1) { v = MT[(size_t)(128 + c) * 512 + k];       dh = wn_hi + 16384;  dl = wn_lo + 16384; }
  else if (arr == 2) { v = M[(size_t)(128 + c) * 512 + k];        dh = wn_hi + 32768;  dl = wn_lo + 32768; }
  else if (arr == 3) { v = MT[(size_t)(128 + c) * 512 + 128 + k]; dh = m11_hi;         dl = m11_lo; }
  else               { v = Wl[(size_t)c * 128 + k];               dh = wl_hi;          dl = wl_lo; }
  unsigned short h = f2bf(v);
  float r = v - bf2f(h);
  dh[j16] = (short)h;
  dl[j16] = (short)f2bf(r);
}

// ---------------- per-query vectors (f64 acc) ----------------
__global__ void k_pq(const float* __restrict__ M, const float* __restrict__ MT,
                     const float* __restrict__ qsA, const float* __restrict__ qrA,
                     float* __restrict__ Qv, double* __restrict__ cq) {
  int b = blockIdx.x, d = threadIdx.x;  // 128 threads
  __shared__ float qs[128], qr[128];
  qs[d] = qsA[b * 128 + d];
  qr[d] = qrA[b * 128 + d];
  __syncthreads();
  double uh = 0, ui = 0, ur = 0;
  for (int x = 0; x < 128; x++) {
    double qsx = qs[x], qrx = qr[x];
    uh += qsx * (double)M[(256 + x) * 512 + d]        + qrx * (double)M[(384 + x) * 512 + d];
    ur += qsx * (double)M[(256 + x) * 512 + 128 + d]  + qrx * (double)M[(384 + x) * 512 + 128 + d];
    ui += qsx * (double)MT[(256 + x) * 512 + d]       + qrx * (double)MT[(384 + x) * 512 + d];
    ur += qsx * (double)MT[(256 + x) * 512 + 128 + d] + qrx * (double)MT[(384 + x) * 512 + 128 + d];
  }
  Qv[b * 384 + d]       = (float)uh;
  Qv[b * 384 + 128 + d] = (float)ui;
  Qv[b * 384 + 256 + d] = (float)ur;
  double t1 = 0, t2 = 0;
  for (int y = 0; y < 128; y++) {
    double qsy = qs[y], qry = qr[y];
    t1 += qsy * (double)MT[(256 + y) * 512 + 256 + d] + qry * (double)MT[(384 + y) * 512 + 256 + d];
    t2 += qsy * (double)MT[(256 + y) * 512 + 384 + d] + qry * (double)MT[(384 + y) * 512 + 384 + d];
  }
  double cp = (double)qs[d] * t1 + (double)qr[d] * t2;
  for (int off = 32; off; off >>= 1) cp += __shfl_down(cp, off, 64);
  __shared__ double red[2];
  if ((d & 63) == 0) red[d >> 6] = cp;
  __syncthreads();
  if (d == 0) cq[b] = red[0] + red[1];
}

// ---------------- T = node_repr @ Wnode via MFMA, A + B(frag-order) in LDS ----------------
__global__ __launch_bounds__(512) void k_gemm_node(const float* __restrict__ A,
                                                   const short* __restrict__ WT_hi,
                                                   const short* __restrict__ WT_lo,
                                                   float* __restrict__ T) {
  __shared__ __align__(16) float As[64][132];
  __shared__ __align__(16) short Bh[16384];
  __shared__ __align__(16) short Bl[16384];
  int t = threadIdx.x;
  int b = blockIdx.x;
  int row0 = (b / 3) * 64;
  int panel = b % 3;
  const short* sh = WT_hi + panel * 16384;
  const short* sl = WT_lo + panel * 16384;
#pragma unroll
  for (int i = 0; i < 4; i++) {
    int fi = t + i * 512;  // 0..2047
    int r = fi >> 5, c4 = (fi & 31) * 4;
    float4 v = make_float4(0.f, 0.f, 0.f, 0.f);
    if (row0 + r < NN) v = *(const float4*)(A + (size_t)(row0 + r) * 128 + c4);
    *(float4*)&As[r][c4] = v;
    *(bf16x8*)&Bh[fi * 8] = *(const bf16x8*)(sh + fi * 8);
    *(bf16x8*)&Bl[fi * 8] = *(const bf16x8*)(sl + fi * 8);
  }
  __syncthreads();
  int w = t >> 6, l = t & 63;
  int rt = w & 3;            // 16-row tile
  int c0 = (w >> 2) * 4;     // ct base: 0 or 4
  int rloc = rt * 16 + (l & 15);
  int kq = (l >> 4) * 8;
  f32x4 acc[4];
#pragma unroll
  for (int cc = 0; cc < 4; cc++)
#pragma unroll
    for (int j = 0; j < 4; j++) acc[cc][j] = 0.f;
#pragma unroll
  for (int kt = 0; kt < 4; kt++) {
    int kb = kt * 32 + kq;
    float4 x = *(const float4*)&As[rloc][kb];
    float4 y = *(const float4*)&As[rloc][kb + 4];
    bf16x8 ah, al;
    cvt8(x, y, ah, al);
#pragma unroll
    for (int cc = 0; cc < 4; cc++) {
      int off = (((c0 + cc) * 4 + kt) * 64 + l) * 8;
      bf16x8 bhv = *(const bf16x8*)&Bh[off];
      bf16x8 blv = *(const bf16x8*)&Bl[off];
      acc[cc] = __builtin_amdgcn_mfma_f32_16x16x32_bf16(ah, bhv, acc[cc], 0, 0, 0);
      acc[cc] = __builtin_amdgcn_mfma_f32_16x16x32_bf16(al, bhv, acc[cc], 0, 0, 0);
      acc[cc] = __builtin_amdgcn_mfma_f32_16x16x32_bf16(ah, blv, acc[cc], 0, 0, 0);
    }
  }
  int rbase = row0 + rt * 16 + (l >> 4) * 4;
#pragma unroll
  for (int cc = 0; cc < 4; cc++) {
    int c = panel * 128 + (c0 + cc) * 16 + (l & 15);
#pragma unroll
    for (int reg = 0; reg < 4; reg++) {
      int r = rbase + reg;
      if (r < NN) T[(size_t)r * 384 + c] = acc[cc][reg];
    }
  }
}

// ---------------- q11[e] = r^T M11 r via MFMA, 128-edge tiles ----------------
__global__ __launch_bounds__(512) void k_q11(const float* __restrict__ rel,
                                             const short* __restrict__ M11T_hi,
                                             const short* __restrict__ M11T_lo,
                                             float* __restrict__ q11) {
  __shared__ __align__(16) float Rs[128][132];
  __shared__ __align__(16) short Bh[16384];
  __shared__ __align__(16) short Bl[16384];
  int t = threadIdx.x;
  int e0 = blockIdx.x * 128;
#pragma unroll
  for (int i = 0; i < 8; i++) {
    int fi = t + i * 512;  // 0..4095
    int r = fi >> 5, c4 = (fi & 31) * 4;
    *(float4*)&Rs[r][c4] = *(const float4*)(rel + (size_t)(e0 + r) * 128 + c4);
  }
#pragma unroll
  for (int i = 0; i < 4; i++) {
    int fi = t + i * 512;
    *(bf16x8*)&Bh[fi * 8] = *(const bf16x8*)(M11T_hi + fi * 8);
    *(bf16x8*)&Bl[fi * 8] = *(const bf16x8*)(M11T_lo + fi * 8);
  }
  __syncthreads();
  int w = t >> 6, l = t & 63;
  int rloc = w * 16 + (l & 15);
  int kq = (l >> 4) * 8;
  f32x4 acc[8];
#pragma unroll
  for (int ct = 0; ct < 8; ct++)
#pragma unroll
    for (int j = 0; j < 4; j++) acc[ct][j] = 0.f;
#pragma unroll
  for (int kt = 0; kt < 4; kt++) {
    int kb = kt * 32 + kq;
    float4 x = *(const float4*)&Rs[rloc][kb];
    float4 y = *(const float4*)&Rs[rloc][kb + 4];
    bf16x8 ah, al;
    cvt8(x, y, ah, al);
#pragma unroll
    for (int ct = 0; ct < 8; ct++) {
      int off = ((ct * 4 + kt) * 64 + l) * 8;
      bf16x8 bhv = *(const bf16x8*)&Bh[off];
      bf16x8 blv = *(const bf16x8*)&Bl[off];
      acc[ct] = __builtin_amdgcn_mfma_f32_16x16x32_bf16(ah, bhv, acc[ct], 0, 0, 0);
      acc[ct] = __builtin_amdgcn_mfma_f32_16x16x32_bf16(al, bhv, acc[ct], 0, 0, 0);
      acc[ct] = __builtin_amdgcn_mfma_f32_16x16x32_bf16(ah, blv, acc[ct], 0, 0, 0);
    }
  }
  // dot P row with R row, reduce across 16-lane col groups
  int rq = (l >> 4) * 4;
  float p[4] = {0.f, 0.f, 0.f, 0.f};
#pragma unroll
  for (int ct = 0; ct < 8; ct++) {
    int c = ct * 16 + (l & 15);
#pragma unroll
    for (int reg = 0; reg < 4; reg++)
      p[reg] += acc[ct][reg] * Rs[w * 16 + rq + reg][c];
  }
#pragma unroll
  for (int reg = 0; reg < 4; reg++) {
    p[reg] += __shfl_xor(p[reg], 1, 64);
    p[reg] += __shfl_xor(p[reg], 2, 64);
    p[reg] += __shfl_xor(p[reg], 4, 64);
    p[reg] += __shfl_xor(p[reg], 8, 64);
  }
  if ((l & 15) == 0) {
#pragma unroll
    for (int reg = 0; reg < 4; reg++) q11[e0 + w * 16 + rq + reg] = p[reg];
  }
}

// ---------------- per-edge logits (wave per edge) + segment max ----------------
__global__ void k_logits(const int* __restrict__ edges, const float* __restrict__ nrep,
                         const float* __restrict__ rel, const float* __restrict__ T,
                         const float* __restrict__ Qv, const double* __restrict__ cq,
                         const float* __restrict__ q11, double* __restrict__ logits,
                         ull* __restrict__ menc) {
  int lane = threadIdx.x & 63;
  int wid = blockIdx.x * (blockDim.x >> 6) + (threadIdx.x >> 6);
  int nw = gridDim.x * (blockDim.x >> 6);
  for (int e = wid; e < EE; e += nw) {
    int eg = edges[(size_t)e * 8 + 0];
    int vi = edges[(size_t)e * 8 + 6];
    int vj = edges[(size_t)e * 8 + 7];
    const float* Tvi = T + (size_t)vi * 384;
    const float* Tvj = T + (size_t)vj * 384;
    const float* q = Qv + (size_t)eg * 384;
    const float* hi = nrep + (size_t)vi * 128;
    const float* hj = nrep + (size_t)vj * 128;
    const float* re = rel + (size_t)e * 128;
    int d0 = lane * 2;
    float2 g   = *(const float2*)&Tvi[d0];
    float2 h1  = *(const float2*)&Tvi[128 + d0];
    float2 jj  = *(const float2*)&Tvj[256 + d0];
    float2 uh  = *(const float2*)&q[d0];
    float2 uiq = *(const float2*)&q[128 + d0];
    float2 urq = *(const float2*)&q[256 + d0];
    float2 hvi = *(const float2*)&hi[d0];
    float2 hvj = *(const float2*)&hj[d0];
    float2 rr  = *(const float2*)&re[d0];
    float v = (g.x + uh.x) * hvj.x + (g.y + uh.y) * hvj.y
            + uiq.x * hvi.x + uiq.y * hvi.y
            + (h1.x + jj.x + urq.x) * rr.x
            + (h1.y + jj.y + urq.y) * rr.y;
    for (int off = 32; off; off >>= 1) v += __shfl_down(v, off, 64);
    if (lane == 0) {
      double l2 = (double)v + cq[eg] + (double)q11[e];
      logits[e] = l2;
      atomicMax(&menc[vi], enc64(l2));
    }
  }
}

// ---------------- exp + segment sum (f64) ----------------
__global__ void k_exp(const int* __restrict__ edges, const ull* __restrict__ menc,
                      const double* __restrict__ logits, double* __restrict__ ex,
                      double* __restrict__ s) {
  int i = blockIdx.x * 256 + threadIdx.x;
  int st = gridDim.x * 256;
  for (int e = i; e < EE; e += st) {
    int vi = edges[(size_t)e * 8 + 6];
    double m = dec64(menc[vi]);
    double v = exp(logits[e] - m);
    ex[e] = v;
    atomicAdd(&s[vi], v);
  }
}

__global__ void k_zero_agg(float4* __restrict__ agg) {
  int i = blockIdx.x * 256 + threadIdx.x;
  int st = gridDim.x * 256;
  const int n4 = NN * 32;
  for (int n = i; n < n4; n += st) agg[n] = make_float4(0.f, 0.f, 0.f, 0.f);
}

// ---------------- top-20 per query (lower-index tie-break) + scatter ----------------
__global__ void k_topk(const double* __restrict__ ex, const double* __restrict__ s,
                       const float* __restrict__ nscore, const int* __restrict__ edges,
                       const float* __restrict__ nrep, float* __restrict__ out_score,
                       float* __restrict__ agg, float* __restrict__ appears) {
  int b = blockIdx.x, t = threadIdx.x;  // 256 threads
  int e = b * 256 + t;
  int vi_t = edges[(size_t)e * 8 + 6];
  double v = ex[e] / s[vi_t] * (double)nscore[vi_t];
  __shared__ double wv[4];
  __shared__ int wi[4];
  __shared__ int winners[KTOP];
  for (int k = 0; k < KTOP; k++) {
    double bv = v;
    int bi = t;
    for (int off = 32; off; off >>= 1) {
      double ov = __shfl_down(bv, off, 64);
      int oi = __shfl_down(bi, off, 64);
      if (ov > bv || (ov == bv && oi < bi)) { bv = ov; bi = oi; }
    }
    if ((t & 63) == 0) { wv[t >> 6] = bv; wi[t >> 6] = bi; }
    __syncthreads();
    if (t == 0) {
      double best = wv[0];
      int besti = wi[0];
      for (int w = 1; w < 4; w++)
        if (wv[w] > best || (wv[w] == best && wi[w] < besti)) { best = wv[w]; besti = wi[w]; }
      winners[k] = besti;
    }
    __syncthreads();
    if (t == winners[k]) v = -1.0;
  }
  for (int k = 0; k < KTOP; k++) {
    int we = b * 256 + winners[k];
    int vi = edges[(size_t)we * 8 + 6];
    int vj = edges[(size_t)we * 8 + 7];
    double sm = ex[we] / s[vi];
    if (t < 128) {
      atomicAdd(&agg[(size_t)vi * 128 + t], (float)sm * nrep[(size_t)vj * 128 + t]);
    } else if (t == 128) {
      atomicAdd(&out_score[vj], (float)(sm * (double)nscore[vi]));
    } else if (t == 129) {
      appears[vi] = 1.f;
    }
  }
}

// ---------------- final: leaky_relu((agg + coef*h) @ W_lin^T + b) via MFMA ----------------
__global__ __launch_bounds__(512) void k_final(const float* __restrict__ agg,
                                               const float* __restrict__ appears,
                                               const float* __restrict__ nrep,
                                               const short* __restrict__ Wl_hi,
                                               const short* __restrict__ Wl_lo,
                                               const float* __restrict__ bl,
                                               float* __restrict__ outr) {
  __shared__ __align__(16) float Xs[64][132];
  __shared__ __align__(16) short Bh[16384];
  __shared__ __align__(16) short Bl[16384];
  int t = threadIdx.x;
  int row0 = blockIdx.x * 64;
#pragma unroll
  for (int i = 0; i < 4; i++) {
    int fi = t + i * 512;
    int r = fi >> 5, c4 = (fi & 31) * 4;
    int rr = row0 + r;
    float4 v = make_float4(0.f, 0.f, 0.f, 0.f);
    if (rr < NN) {
      float4 ag = *(const float4*)(agg + (size_t)rr * 128 + c4);
      float4 h = *(const float4*)(nrep + (size_t)rr * 128 + c4);
      float coef = (appears[rr] > 0.f) ? 0.f : 1.f;
      v.x = ag.x + coef * h.x;
      v.y = ag.y + coef * h.y;
      v.z = ag.z + coef * h.z;
      v.w = ag.w + coef * h.w;
    }
    *(float4*)&Xs[r][c4] = v;
    *(bf16x8*)&Bh[fi * 8] = *(const bf16x8*)(Wl_hi + fi * 8);
    *(bf16x8*)&Bl[fi * 8] = *(const bf16x8*)(Wl_lo + fi * 8);
  }
  __syncthreads();
  int w = t >> 6, l = t & 63;
  int rt = w & 3;
  int c0 = (w >> 2) * 4;
  int rloc = rt * 16 + (l & 15);
  int kq = (l >> 4) * 8;
  f32x4 acc[4];
#pragma unroll
  for (int cc = 0; cc < 4; cc++)
#pragma unroll
    for (int j = 0; j < 4; j++) acc[cc][j] = 0.f;
#pragma unroll
  for (int kt = 0; kt < 4; kt++) {
    int kb = kt * 32 + kq;
    float4 x = *(const float4*)&Xs[rloc][kb];
    float4 y = *(const float4*)&Xs[rloc][kb + 4];
    bf16x8 ah, al;
    cvt8(x, y, ah, al);
#pragma unroll
    for (int cc = 0; cc < 4; cc++) {
      int off = (((c0 + cc) * 4 + kt) * 64 + l) * 8;
      bf16x8 bhv = *(const bf16x8*)&Bh[off];
      bf16x8 blv = *(const bf16x8*)&Bl[off];
      acc[cc] = __builtin_amdgcn_mfma_f32_16x16x32_bf16(ah, bhv, acc[cc], 0, 0, 0);
      acc[cc] = __builtin_amdgcn_mfma_f32_16x16x32_bf16(al, bhv, acc[cc], 0, 0, 0);
      acc[cc] = __builtin_amdgcn_mfma_f32_16x16x32_bf16(ah, blv, acc[cc], 0, 0, 0);
    }
  }
  int rbase = row0 + rt * 16 + (l >> 4) * 4;
#pragma unroll
  for (int cc = 0; cc < 4; cc++) {
    int c = (c0 + cc) * 16 + (l & 15);
#pragma unroll
    for (int reg = 0; reg < 4; reg++) {
      int r = rbase + reg;
      if (r < NN) {
        float y = acc[cc][reg] + bl[c];
        outr[(size_t)r * 128 + c] = (y > 0.f) ? y : 0.01f * y;
      }
    }
  }
}

extern "C" void kernel_launch(void* const* d_in, const int* in_sizes, int n_in,
                              void* d_out, int out_size, void* d_ws, size_t ws_size,
                              hipStream_t stream) {
  const float* node_score = (const float*)d_in[0];
  const float* node_repr  = (const float*)d_in[1];
  const float* rel_emb    = (const float*)d_in[2];
  const float* q_src      = (const float*)d_in[3];
  const float* q_rel      = (const float*)d_in[4];
  const float* Wq         = (const float*)d_in[5];
  const float* Wk         = (const float*)d_in[6];
  const float* W_lin      = (const float*)d_in[7];
  const float* b_lin      = (const float*)d_in[8];
  const int*   edges      = (const int*)d_in[9];

  char* ws = (char*)d_ws;
  size_t off = 0;
  auto carve = [&](size_t bytes) -> void* {
    void* p = ws + off;
    off += (bytes + 255) & ~(size_t)255;
    return p;
  };
  float*  M      = (float*)carve(512 * 512 * 4);
  float*  MT     = (float*)carve(512 * 512 * 4);
  short*  wn_hi  = (short*)carve(3 * 16384 * 2);
  short*  wn_lo  = (short*)carve(3 * 16384 * 2);
  short*  m11_hi = (short*)carve(16384 * 2);
  short*  m11_lo = (short*)carve(16384 * 2);
  short*  wl_hi  = (short*)carve(16384 * 2);
  short*  wl_lo  = (short*)carve(16384 * 2);
  float*  Qv     = (float*)carve((size_t)BQ * 384 * 4);
  double* cq     = (double*)carve((size_t)BQ * 8);
  double* logits = (double*)carve((size_t)EE * 8);
  float*  q11    = (float*)carve((size_t)EE * 4);
  ull*    menc   = (ull*)carve((size_t)NN * 8);
  double* s      = (double*)carve((size_t)NN * 8);
  double* ex     = (double*)carve((size_t)EE * 8);
  float*  appears= (float*)carve((size_t)NN * 4);
  float*  T      = (float*)carve((size_t)NN * 384 * 4);
  float*  agg    = T;  // alias: T dead after k_logits; zeroed before reuse

  float* out_score = (float*)d_out;
  float* out_repr  = (float*)d_out + NN;

  k_init<<<512, 256, 0, stream>>>(menc, s, appears, out_score);
  k_matM<<<dim3(512, 2), 256, 0, stream>>>(Wq, Wk, M);
  k_transpose<<<dim3(512, 2), 256, 0, stream>>>(M, MT);
  k_pack<<<320, 256, 0, stream>>>(M, MT, W_lin, wn_hi, wn_lo, m11_hi, m11_lo, wl_hi, wl_lo);
  k_pq<<<BQ, 128, 0, stream>>>(M, MT, q_src, q_rel, Qv, cq);
  k_gemm_node<<<1563 * 3, 512, 0, stream>>>(node_repr, wn_hi, wn_lo, T);
  k_q11<<<2048, 512, 0, stream>>>(rel_emb, m11_hi, m11_lo, q11);
  k_logits<<<2048, 256, 0, stream>>>(edges, node_repr, rel_emb, T, Qv, cq, q11, logits, menc);
  k_zero_agg<<<2048, 256, 0, stream>>>((float4*)agg);
  k_exp<<<1024, 256, 0, stream>>>(edges, menc, logits, ex, s);
  k_topk<<<BQ, 256, 0, stream>>>(ex, s, node_score, edges, node_repr, out_score, agg, appears);
  k_final<<<1563, 512, 0, stream>>>(agg, appears, node_repr, wl_hi, wl_lo, b_lin, out_repr);
}

// Round 5
// 505.611 us; speedup vs baseline: 1.5063x; 1.0605x over previous
//
#include <hip/hip_runtime.h>

#define NN 100000
#define BQ 1024
#define EE 262144
#define KTOP 20

typedef unsigned long long ull;
typedef __attribute__((ext_vector_type(8))) short bf16x8;
typedef __attribute__((ext_vector_type(4))) float f32x4;

__device__ __forceinline__ ull enc64(double d) {
  ull u = (ull)__double_as_longlong(d);
  return (u >> 63) ? ~u : (u | 0x8000000000000000ull);
}
__device__ __forceinline__ double dec64(ull u) {
  ull b = (u >> 63) ? (u & 0x7FFFFFFFFFFFFFFFull) : ~u;
  return __longlong_as_double((long long)b);
}

__device__ __forceinline__ unsigned short f2bf(float f) {
  unsigned u = __float_as_uint(f);
  u += 0x7fff + ((u >> 16) & 1);
  return (unsigned short)(u >> 16);
}
__device__ __forceinline__ float bf2f(unsigned short h) {
  return __uint_as_float(((unsigned)h) << 16);
}
// 8 f32 -> hi/lo bf16 fragments
__device__ __forceinline__ void cvt8(float4 x, float4 y, bf16x8& hi, bf16x8& lo) {
  float a[8] = {x.x, x.y, x.z, x.w, y.x, y.y, y.z, y.w};
#pragma unroll
  for (int j = 0; j < 8; j++) {
    unsigned short h = f2bf(a[j]);
    float r = a[j] - bf2f(h);
    hi[j] = (short)h;
    lo[j] = (short)f2bf(r);
  }
}

// ---------------- init ----------------
__global__ void k_init(ull* __restrict__ menc, double* __restrict__ s,
                       float* __restrict__ appears, float* __restrict__ out_score) {
  int i = blockIdx.x * 256 + threadIdx.x;
  int st = gridDim.x * 256;
  for (int n = i; n < NN; n += st) {
    menc[n] = 0ull;
    s[n] = 0.0;
    appears[n] = 0.f;
    out_score[n] = 0.f;
  }
}

// ---------------- M = Wq^T Wk (f64 acc, f32 store) ----------------
__global__ void k_matM(const float* __restrict__ Wq, const float* __restrict__ Wk,
                       float* __restrict__ M) {
  int x = blockIdx.x;
  int y = blockIdx.y * 256 + threadIdx.x;
  double acc = 0.0;
  for (int a = 0; a < 512; a++)
    acc += (double)Wq[a * 512 + x] * (double)Wk[a * 512 + y];
  M[x * 512 + y] = (float)acc;
}

__global__ void k_transpose(const float* __restrict__ M, float* __restrict__ MT) {
  int x = blockIdx.x;
  int y = blockIdx.y * 256 + threadIdx.x;
  MT[y * 512 + x] = M[x * 512 + y];
}

// ---------------- pack B operands as bf16 hi/lo in FRAGMENT ORDER ----------------
// chunk g = ct*4+kt, lane l, elem j: dest[(g*64+l)*8+j] = BT[c][k],
//   c = ct*16 + (l&15), k = kt*32 + (l>>4)*8 + j
__global__ void k_pack(const float* __restrict__ M, const float* __restrict__ MT,
                       const float* __restrict__ Wl,
                       short* __restrict__ wn_hi, short* __restrict__ wn_lo,
                       short* __restrict__ m11_hi, short* __restrict__ m11_lo,
                       short* __restrict__ wl_hi, short* __restrict__ wl_lo) {
  int idx = blockIdx.x * 256 + threadIdx.x;
  if (idx >= 5 * 16384) return;
  int arr = idx >> 14;
  int j16 = idx & 16383;
  int g = j16 >> 9;
  int l = (j16 >> 3) & 63;
  int jj = j16 & 7;
  int c = (g >> 2) * 16 + (l & 15);
  int k = (g & 3) * 32 + ((l >> 4) << 3) + jj;
  float v;
  short *dh, *dl;
  if (arr == 0)      { v = MT[(size_t)c * 512 + k];               dh = wn_hi;          dl = wn_lo; }
  else if (arr == 1) { v = MT[(size_t)(128 + c) * 512 + k];       dh = wn_hi + 16384;  dl = wn_lo + 16384; }
  else if (arr == 2) { v = M[(size_t)(128 + c) * 512 + k];        dh = wn_hi + 32768;  dl = wn_lo + 32768; }
  else if (arr == 3) { v = MT[(size_t)(128 + c) * 512 + 128 + k]; dh = m11_hi;         dl = m11_lo; }
  else               { v = Wl[(size_t)c * 128 + k];               dh = wl_hi;          dl = wl_lo; }
  unsigned short h = f2bf(v);
  float r = v - bf2f(h);
  dh[j16] = (short)h;
  dl[j16] = (short)f2bf(r);
}

// ---------------- per-query vectors (f64 acc) ----------------
__global__ void k_pq(const float* __restrict__ M, const float* __restrict__ MT,
                     const float* __restrict__ qsA, const float* __restrict__ qrA,
                     float* __restrict__ Qv, double* __restrict__ cq) {
  int b = blockIdx.x, d = threadIdx.x;  // 128 threads
  __shared__ float qs[128], qr[128];
  qs[d] = qsA[b * 128 + d];
  qr[d] = qrA[b * 128 + d];
  __syncthreads();
  double uh = 0, ui = 0, ur = 0;
  for (int x = 0; x < 128; x++) {
    double qsx = qs[x], qrx = qr[x];
    uh += qsx * (double)M[(256 + x) * 512 + d]        + qrx * (double)M[(384 + x) * 512 + d];
    ur += qsx * (double)M[(256 + x) * 512 + 128 + d]  + qrx * (double)M[(384 + x) * 512 + 128 + d];
    ui += qsx * (double)MT[(256 + x) * 512 + d]       + qrx * (double)MT[(384 + x) * 512 + d];
    ur += qsx * (double)MT[(256 + x) * 512 + 128 + d] + qrx * (double)MT[(384 + x) * 512 + 128 + d];
  }
  Qv[b * 384 + d]       = (float)uh;
  Qv[b * 384 + 128 + d] = (float)ui;
  Qv[b * 384 + 256 + d] = (float)ur;
  double t1 = 0, t2 = 0;
  for (int y = 0; y < 128; y++) {
    double qsy = qs[y], qry = qr[y];
    t1 += qsy * (double)MT[(256 + y) * 512 + 256 + d] + qry * (double)MT[(384 + y) * 512 + 256 + d];
    t2 += qsy * (double)MT[(256 + y) * 512 + 384 + d] + qry * (double)MT[(384 + y) * 512 + 384 + d];
  }
  double cp = (double)qs[d] * t1 + (double)qr[d] * t2;
  for (int off = 32; off; off >>= 1) cp += __shfl_down(cp, off, 64);
  __shared__ double red[2];
  if ((d & 63) == 0) red[d >> 6] = cp;
  __syncthreads();
  if (d == 0) cq[b] = red[0] + red[1];
}

// ---------------- node transforms via MFMA -> P1[n][256]=[G|H1], J[n][128] ----------------
__global__ __launch_bounds__(512) void k_gemm_node(const float* __restrict__ A,
                                                   const short* __restrict__ WT_hi,
                                                   const short* __restrict__ WT_lo,
                                                   float* __restrict__ P1,
                                                   float* __restrict__ J) {
  __shared__ __align__(16) float As[64][132];
  __shared__ __align__(16) short Bh[16384];
  __shared__ __align__(16) short Bl[16384];
  int t = threadIdx.x;
  int b = blockIdx.x;
  int row0 = (b / 3) * 64;
  int panel = b % 3;
  const short* sh = WT_hi + panel * 16384;
  const short* sl = WT_lo + panel * 16384;
#pragma unroll
  for (int i = 0; i < 4; i++) {
    int fi = t + i * 512;
    int r = fi >> 5, c4 = (fi & 31) * 4;
    float4 v = make_float4(0.f, 0.f, 0.f, 0.f);
    if (row0 + r < NN) v = *(const float4*)(A + (size_t)(row0 + r) * 128 + c4);
    *(float4*)&As[r][c4] = v;
    *(bf16x8*)&Bh[fi * 8] = *(const bf16x8*)(sh + fi * 8);
    *(bf16x8*)&Bl[fi * 8] = *(const bf16x8*)(sl + fi * 8);
  }
  __syncthreads();
  int w = t >> 6, l = t & 63;
  int rt = w & 3;
  int c0 = (w >> 2) * 4;
  int rloc = rt * 16 + (l & 15);
  int kq = (l >> 4) * 8;
  f32x4 acc[4];
#pragma unroll
  for (int cc = 0; cc < 4; cc++)
#pragma unroll
    for (int j = 0; j < 4; j++) acc[cc][j] = 0.f;
#pragma unroll
  for (int kt = 0; kt < 4; kt++) {
    int kb = kt * 32 + kq;
    float4 x = *(const float4*)&As[rloc][kb];
    float4 y = *(const float4*)&As[rloc][kb + 4];
    bf16x8 ah, al;
    cvt8(x, y, ah, al);
#pragma unroll
    for (int cc = 0; cc < 4; cc++) {
      int off = (((c0 + cc) * 4 + kt) * 64 + l) * 8;
      bf16x8 bhv = *(const bf16x8*)&Bh[off];
      bf16x8 blv = *(const bf16x8*)&Bl[off];
      acc[cc] = __builtin_amdgcn_mfma_f32_16x16x32_bf16(ah, bhv, acc[cc], 0, 0, 0);
      acc[cc] = __builtin_amdgcn_mfma_f32_16x16x32_bf16(al, bhv, acc[cc], 0, 0, 0);
      acc[cc] = __builtin_amdgcn_mfma_f32_16x16x32_bf16(ah, blv, acc[cc], 0, 0, 0);
    }
  }
  int rbase = row0 + rt * 16 + (l >> 4) * 4;
#pragma unroll
  for (int cc = 0; cc < 4; cc++) {
    int col = (c0 + cc) * 16 + (l & 15);
#pragma unroll
    for (int reg = 0; reg < 4; reg++) {
      int r = rbase + reg;
      if (r < NN) {
        if (panel < 2) P1[(size_t)r * 256 + panel * 128 + col] = acc[cc][reg];
        else           J[(size_t)r * 128 + col] = acc[cc][reg];
      }
    }
  }
}

// ---------------- q11[e] = r^T M11 r via MFMA, 128-edge tiles ----------------
__global__ __launch_bounds__(512) void k_q11(const float* __restrict__ rel,
                                             const short* __restrict__ M11T_hi,
                                             const short* __restrict__ M11T_lo,
                                             float* __restrict__ q11) {
  __shared__ __align__(16) float Rs[128][132];
  __shared__ __align__(16) short Bh[16384];
  __shared__ __align__(16) short Bl[16384];
  int t = threadIdx.x;
  int e0 = blockIdx.x * 128;
#pragma unroll
  for (int i = 0; i < 8; i++) {
    int fi = t + i * 512;
    int r = fi >> 5, c4 = (fi & 31) * 4;
    *(float4*)&Rs[r][c4] = *(const float4*)(rel + (size_t)(e0 + r) * 128 + c4);
  }
#pragma unroll
  for (int i = 0; i < 4; i++) {
    int fi = t + i * 512;
    *(bf16x8*)&Bh[fi * 8] = *(const bf16x8*)(M11T_hi + fi * 8);
    *(bf16x8*)&Bl[fi * 8] = *(const bf16x8*)(M11T_lo + fi * 8);
  }
  __syncthreads();
  int w = t >> 6, l = t & 63;
  int rloc = w * 16 + (l & 15);
  int kq = (l >> 4) * 8;
  f32x4 acc[8];
#pragma unroll
  for (int ct = 0; ct < 8; ct++)
#pragma unroll
    for (int j = 0; j < 4; j++) acc[ct][j] = 0.f;
#pragma unroll
  for (int kt = 0; kt < 4; kt++) {
    int kb = kt * 32 + kq;
    float4 x = *(const float4*)&Rs[rloc][kb];
    float4 y = *(const float4*)&Rs[rloc][kb + 4];
    bf16x8 ah, al;
    cvt8(x, y, ah, al);
#pragma unroll
    for (int ct = 0; ct < 8; ct++) {
      int off = ((ct * 4 + kt) * 64 + l) * 8;
      bf16x8 bhv = *(const bf16x8*)&Bh[off];
      bf16x8 blv = *(const bf16x8*)&Bl[off];
      acc[ct] = __builtin_amdgcn_mfma_f32_16x16x32_bf16(ah, bhv, acc[ct], 0, 0, 0);
      acc[ct] = __builtin_amdgcn_mfma_f32_16x16x32_bf16(al, bhv, acc[ct], 0, 0, 0);
      acc[ct] = __builtin_amdgcn_mfma_f32_16x16x32_bf16(ah, blv, acc[ct], 0, 0, 0);
    }
  }
  int rq = (l >> 4) * 4;
  float p[4] = {0.f, 0.f, 0.f, 0.f};
#pragma unroll
  for (int ct = 0; ct < 8; ct++) {
    int c = ct * 16 + (l & 15);
#pragma unroll
    for (int reg = 0; reg < 4; reg++)
      p[reg] += acc[ct][reg] * Rs[w * 16 + rq + reg][c];
  }
#pragma unroll
  for (int reg = 0; reg < 4; reg++) {
    p[reg] += __shfl_xor(p[reg], 1, 64);
    p[reg] += __shfl_xor(p[reg], 2, 64);
    p[reg] += __shfl_xor(p[reg], 4, 64);
    p[reg] += __shfl_xor(p[reg], 8, 64);
  }
  if ((l & 15) == 0) {
#pragma unroll
    for (int reg = 0; reg < 4; reg++) q11[e0 + w * 16 + rq + reg] = p[reg];
  }
}

// ---------------- per-edge logits: 16 lanes per edge, float4 gathers ----------------
__global__ __launch_bounds__(256) void k_logits(const int* __restrict__ edges,
                                                const float* __restrict__ nrep,
                                                const float* __restrict__ rel,
                                                const float* __restrict__ P1,
                                                const float* __restrict__ J,
                                                const float* __restrict__ Qv,
                                                const double* __restrict__ cq,
                                                const float* __restrict__ q11,
                                                double* __restrict__ logits,
                                                ull* __restrict__ menc) {
  int t = threadIdx.x;
  int ll = t & 15;           // lane within 16-group
  int grp = (t & 63) >> 4;   // 0..3: edge within wave
  int wid = blockIdx.x * 4 + (t >> 6);
  int nw = gridDim.x * 4;
  int d = ll * 8;
  for (int e4 = wid; e4 < EE / 4; e4 += nw) {
    int e = e4 * 4 + grp;
    int eg = edges[(size_t)e * 8 + 0];
    int vi = edges[(size_t)e * 8 + 6];
    int vj = edges[(size_t)e * 8 + 7];
    const float* pvi = P1 + (size_t)vi * 256 + d;
    const float* jv  = J + (size_t)vj * 128 + d;
    const float* hi  = nrep + (size_t)vi * 128 + d;
    const float* hj  = nrep + (size_t)vj * 128 + d;
    const float* re  = rel + (size_t)e * 128 + d;
    const float* q   = Qv + (size_t)eg * 384 + d;
    float4 g0  = *(const float4*)pvi,         g1  = *(const float4*)(pvi + 4);
    float4 h10 = *(const float4*)(pvi + 128), h11 = *(const float4*)(pvi + 132);
    float4 j0  = *(const float4*)jv,          j1  = *(const float4*)(jv + 4);
    float4 a0  = *(const float4*)hi,          a1  = *(const float4*)(hi + 4);
    float4 b0  = *(const float4*)hj,          b1  = *(const float4*)(hj + 4);
    float4 r0  = *(const float4*)re,          r1  = *(const float4*)(re + 4);
    float4 uh0 = *(const float4*)q,           uh1 = *(const float4*)(q + 4);
    float4 ui0 = *(const float4*)(q + 128),   ui1 = *(const float4*)(q + 132);
    float4 ur0 = *(const float4*)(q + 256),   ur1 = *(const float4*)(q + 260);
    float acc;
    acc  = (g0.x + uh0.x) * b0.x + (g0.y + uh0.y) * b0.y
         + (g0.z + uh0.z) * b0.z + (g0.w + uh0.w) * b0.w
         + (g1.x + uh1.x) * b1.x + (g1.y + uh1.y) * b1.y
         + (g1.z + uh1.z) * b1.z + (g1.w + uh1.w) * b1.w;
    acc += ui0.x * a0.x + ui0.y * a0.y + ui0.z * a0.z + ui0.w * a0.w
         + ui1.x * a1.x + ui1.y * a1.y + ui1.z * a1.z + ui1.w * a1.w;
    acc += (h10.x + j0.x + ur0.x) * r0.x + (h10.y + j0.y + ur0.y) * r0.y
         + (h10.z + j0.z + ur0.z) * r0.z + (h10.w + j0.w + ur0.w) * r0.w
         + (h11.x + j1.x + ur1.x) * r1.x + (h11.y + j1.y + ur1.y) * r1.y
         + (h11.z + j1.z + ur1.z) * r1.z + (h11.w + j1.w + ur1.w) * r1.w;
    acc += __shfl_xor(acc, 1, 64);
    acc += __shfl_xor(acc, 2, 64);
    acc += __shfl_xor(acc, 4, 64);
    acc += __shfl_xor(acc, 8, 64);
    if (ll == 0) {
      double l2 = (double)acc + cq[eg] + (double)q11[e];
      logits[e] = l2;
      atomicMax(&menc[vi], enc64(l2));
    }
  }
}

// ---------------- exp + segment sum (f64) ----------------
__global__ void k_exp(const int* __restrict__ edges, const ull* __restrict__ menc,
                      const double* __restrict__ logits, double* __restrict__ ex,
                      double* __restrict__ s) {
  int i = blockIdx.x * 256 + threadIdx.x;
  int st = gridDim.x * 256;
  for (int e = i; e < EE; e += st) {
    int vi = edges[(size_t)e * 8 + 6];
    double m = dec64(menc[vi]);
    double v = exp(logits[e] - m);
    ex[e] = v;
    atomicAdd(&s[vi], v);
  }
}

__global__ void k_zero_agg(float4* __restrict__ agg) {
  int i = blockIdx.x * 256 + threadIdx.x;
  int st = gridDim.x * 256;
  const int n4 = NN * 32;
  for (int n = i; n < n4; n += st) agg[n] = make_float4(0.f, 0.f, 0.f, 0.f);
}

// ---------------- top-20 per query (lower-index tie-break) + scatter ----------------
__global__ void k_topk(const double* __restrict__ ex, const double* __restrict__ s,
                       const float* __restrict__ nscore, const int* __restrict__ edges,
                       const float* __restrict__ nrep, float* __restrict__ out_score,
                       float* __restrict__ agg, float* __restrict__ appears) {
  int b = blockIdx.x, t = threadIdx.x;  // 256 threads
  int e = b * 256 + t;
  int vi_t = edges[(size_t)e * 8 + 6];
  double v = ex[e] / s[vi_t] * (double)nscore[vi_t];
  __shared__ double wv[4];
  __shared__ int wi[4];
  __shared__ int winners[KTOP];
  for (int k = 0; k < KTOP; k++) {
    double bv = v;
    int bi = t;
    for (int off = 32; off; off >>= 1) {
      double ov = __shfl_down(bv, off, 64);
      int oi = __shfl_down(bi, off, 64);
      if (ov > bv || (ov == bv && oi < bi)) { bv = ov; bi = oi; }
    }
    if ((t & 63) == 0) { wv[t >> 6] = bv; wi[t >> 6] = bi; }
    __syncthreads();
    if (t == 0) {
      double best = wv[0];
      int besti = wi[0];
      for (int w = 1; w < 4; w++)
        if (wv[w] > best || (wv[w] == best && wi[w] < besti)) { best = wv[w]; besti = wi[w]; }
      winners[k] = besti;
    }
    __syncthreads();
    if (t == winners[k]) v = -1.0;
  }
  for (int k = 0; k < KTOP; k++) {
    int we = b * 256 + winners[k];
    int vi = edges[(size_t)we * 8 + 6];
    int vj = edges[(size_t)we * 8 + 7];
    double sm = ex[we] / s[vi];
    if (t < 128) {
      atomicAdd(&agg[(size_t)vi * 128 + t], (float)sm * nrep[(size_t)vj * 128 + t]);
    } else if (t == 128) {
      atomicAdd(&out_score[vj], (float)(sm * (double)nscore[vi]));
    } else if (t == 129) {
      appears[vi] = 1.f;
    }
  }
}

// ---------------- final: leaky_relu((agg + coef*h) @ W_lin^T + b) via MFMA ----------------
__global__ __launch_bounds__(512) void k_final(const float* __restrict__ agg,
                                               const float* __restrict__ appears,
                                               const float* __restrict__ nrep,
                                               const short* __restrict__ Wl_hi,
                                               const short* __restrict__ Wl_lo,
                                               const float* __restrict__ bl,
                                               float* __restrict__ outr) {
  __shared__ __align__(16) float Xs[64][132];
  __shared__ __align__(16) short Bh[16384];
  __shared__ __align__(16) short Bl[16384];
  int t = threadIdx.x;
  int row0 = blockIdx.x * 64;
#pragma unroll
  for (int i = 0; i < 4; i++) {
    int fi = t + i * 512;
    int r = fi >> 5, c4 = (fi & 31) * 4;
    int rr = row0 + r;
    float4 v = make_float4(0.f, 0.f, 0.f, 0.f);
    if (rr < NN) {
      float4 ag = *(const float4*)(agg + (size_t)rr * 128 + c4);
      float4 h = *(const float4*)(nrep + (size_t)rr * 128 + c4);
      float coef = (appears[rr] > 0.f) ? 0.f : 1.f;
      v.x = ag.x + coef * h.x;
      v.y = ag.y + coef * h.y;
      v.z = ag.z + coef * h.z;
      v.w = ag.w + coef * h.w;
    }
    *(float4*)&Xs[r][c4] = v;
    *(bf16x8*)&Bh[fi * 8] = *(const bf16x8*)(Wl_hi + fi * 8);
    *(bf16x8*)&Bl[fi * 8] = *(const bf16x8*)(Wl_lo + fi * 8);
  }
  __syncthreads();
  int w = t >> 6, l = t & 63;
  int rt = w & 3;
  int c0 = (w >> 2) * 4;
  int rloc = rt * 16 + (l & 15);
  int kq = (l >> 4) * 8;
  f32x4 acc[4];
#pragma unroll
  for (int cc = 0; cc < 4; cc++)
#pragma unroll
    for (int j = 0; j < 4; j++) acc[cc][j] = 0.f;
#pragma unroll
  for (int kt = 0; kt < 4; kt++) {
    int kb = kt * 32 + kq;
    float4 x = *(const float4*)&Xs[rloc][kb];
    float4 y = *(const float4*)&Xs[rloc][kb + 4];
    bf16x8 ah, al;
    cvt8(x, y, ah, al);
#pragma unroll
    for (int cc = 0; cc < 4; cc++) {
      int off = (((c0 + cc) * 4 + kt) * 64 + l) * 8;
      bf16x8 bhv = *(const bf16x8*)&Bh[off];
      bf16x8 blv = *(const bf16x8*)&Bl[off];
      acc[cc] = __builtin_amdgcn_mfma_f32_16x16x32_bf16(ah, bhv, acc[cc], 0, 0, 0);
      acc[cc] = __builtin_amdgcn_mfma_f32_16x16x32_bf16(al, bhv, acc[cc], 0, 0, 0);
      acc[cc] = __builtin_amdgcn_mfma_f32_16x16x32_bf16(ah, blv, acc[cc], 0, 0, 0);
    }
  }
  int rbase = row0 + rt * 16 + (l >> 4) * 4;
#pragma unroll
  for (int cc = 0; cc < 4; cc++) {
    int c = (c0 + cc) * 16 + (l & 15);
#pragma unroll
    for (int reg = 0; reg < 4; reg++) {
      int r = rbase + reg;
      if (r < NN) {
        float y = acc[cc][reg] + bl[c];
        outr[(size_t)r * 128 + c] = (y > 0.f) ? y : 0.01f * y;
      }
    }
  }
}

extern "C" void kernel_launch(void* const* d_in, const int* in_sizes, int n_in,
                              void* d_out, int out_size, void* d_ws, size_t ws_size,
                              hipStream_t stream) {
  const float* node_score = (const float*)d_in[0];
  const float* node_repr  = (const float*)d_in[1];
  const float* rel_emb    = (const float*)d_in[2];
  const float* q_src      = (const float*)d_in[3];
  const float* q_rel      = (const float*)d_in[4];
  const float* Wq         = (const float*)d_in[5];
  const float* Wk         = (const float*)d_in[6];
  const float* W_lin      = (const float*)d_in[7];
  const float* b_lin      = (const float*)d_in[8];
  const int*   edges      = (const int*)d_in[9];

  char* ws = (char*)d_ws;
  size_t off = 0;
  auto carve = [&](size_t bytes) -> void* {
    void* p = ws + off;
    off += (bytes + 255) & ~(size_t)255;
    return p;
  };
  float*  M      = (float*)carve(512 * 512 * 4);
  float*  MT     = (float*)carve(512 * 512 * 4);
  short*  wn_hi  = (short*)carve(3 * 16384 * 2);
  short*  wn_lo  = (short*)carve(3 * 16384 * 2);
  short*  m11_hi = (short*)carve(16384 * 2);
  short*  m11_lo = (short*)carve(16384 * 2);
  short*  wl_hi  = (short*)carve(16384 * 2);
  short*  wl_lo  = (short*)carve(16384 * 2);
  float*  Qv     = (float*)carve((size_t)BQ * 384 * 4);
  double* cq     = (double*)carve((size_t)BQ * 8);
  double* logits = (double*)carve((size_t)EE * 8);
  float*  q11    = (float*)carve((size_t)EE * 4);
  ull*    menc   = (ull*)carve((size_t)NN * 8);
  double* s      = (double*)carve((size_t)NN * 8);
  double* ex     = (double*)carve((size_t)EE * 8);
  float*  appears= (float*)carve((size_t)NN * 4);
  float*  P1     = (float*)carve((size_t)NN * 256 * 4);  // [G|H1] per node
  float*  J      = (float*)carve((size_t)NN * 128 * 4);  // J per node
  float*  agg    = P1;  // alias: P1 dead after k_logits; zeroed before reuse

  float* out_score = (float*)d_out;
  float* out_repr  = (float*)d_out + NN;

  k_init<<<512, 256, 0, stream>>>(menc, s, appears, out_score);
  k_matM<<<dim3(512, 2), 256, 0, stream>>>(Wq, Wk, M);
  k_transpose<<<dim3(512, 2), 256, 0, stream>>>(M, MT);
  k_pack<<<320, 256, 0, stream>>>(M, MT, W_lin, wn_hi, wn_lo, m11_hi, m11_lo, wl_hi, wl_lo);
  k_pq<<<BQ, 128, 0, stream>>>(M, MT, q_src, q_rel, Qv, cq);
  k_gemm_node<<<1563 * 3, 512, 0, stream>>>(node_repr, wn_hi, wn_lo, P1, J);
  k_q11<<<2048, 512, 0, stream>>>(rel_emb, m11_hi, m11_lo, q11);
  k_logits<<<8192, 256, 0, stream>>>(edges, node_repr, rel_emb, P1, J, Qv, cq, q11, logits, menc);
  k_zero_agg<<<2048, 256, 0, stream>>>((float4*)agg);
  k_exp<<<1024, 256, 0, stream>>>(edges, menc, logits, ex, s);
  k_topk<<<BQ, 256, 0, stream>>>(ex, s, node_score, edges, node_repr, out_score, agg, appears);
  k_final<<<1563, 512, 0, stream>>>(agg, appears, node_repr, wl_hi, wl_lo, b_lin, out_repr);
}